// Round 5
// baseline (1317.532 us; speedup 1.0000x reference)
//
#include <hip/hip_runtime.h>
#include <hip/hip_bf16.h>
#include <cstdint>

typedef __hip_bfloat16 bf16;
typedef __bf16 b8 __attribute__((ext_vector_type(8)));
typedef float f4v __attribute__((ext_vector_type(4)));
typedef short s8v __attribute__((ext_vector_type(8)));

#define DEVI static __device__ __forceinline__

// async global->LDS, 16B per lane. LDS dest is wave-uniform base + lane*16.
DEVI void gload16(const void* g, void* l) {
  __builtin_amdgcn_global_load_lds(
      (const __attribute__((address_space(1))) void*)(uintptr_t)g,
      (__attribute__((address_space(3))) void*)(uint32_t)(uintptr_t)l,
      16, 0, 0);
}

DEVI f4v mfma_bf16(b8 a, b8 b, f4v c) {
  return __builtin_amdgcn_mfma_f32_16x16x32_bf16(a, b, c, 0, 0, 0);
}

// ---------------------------------------------------------------------------
// prep: x -> xb (bf16); zero m (3x8192x8) + Wc (27x3072) + Wo (27x1024) region
// ---------------------------------------------------------------------------
__global__ void prep_kernel(const float* __restrict__ x, bf16* __restrict__ xb,
                            float* __restrict__ zbase) {
  int gid = blockIdx.x * 256 + threadIdx.x;
  int i = gid * 4;
  float4 v = *(const float4*)(x + i);
  __hip_bfloat162 a, b;
  a.x = __float2bfloat16(v.x); a.y = __float2bfloat16(v.y);
  b.x = __float2bfloat16(v.z); b.y = __float2bfloat16(v.w);
  *(__hip_bfloat162*)(xb + i) = a;
  *(__hip_bfloat162*)(xb + i + 2) = b;
  if (gid < 307200) zbase[gid] = 0.f;  // 196608 m + 82944 Wc + 27648 Wo
}

// ---------------------------------------------------------------------------
// transpose + cast fp32 [R][C] -> bf16 [C][R]   (weights, tiny)
// ---------------------------------------------------------------------------
__global__ void transpose_cast(const float* __restrict__ in, bf16* __restrict__ out,
                               int R, int C) {
  __shared__ float tile[32][33];
  int c0 = blockIdx.x * 32, r0 = blockIdx.y * 32;
  int tx = threadIdx.x & 31, ty = threadIdx.x >> 5;  // 32 x 8
  for (int rr = ty; rr < 32; rr += 8)
    tile[rr][tx] = in[(size_t)(r0 + rr) * C + c0 + tx];
  __syncthreads();
  for (int cc = ty; cc < 32; cc += 8)
    out[(size_t)(c0 + cc) * R + r0 + tx] = __float2bfloat16(tile[tx][cc]);
}

// ---------------------------------------------------------------------------
// wcomb: out[i*9+j][n] = sum_k row(i,j)[k] * Wsrc[k][n]; row j<8 = W_attn[i][j],
// j=8 = b_attn[i]. k split into 8 chunks, atomicAdd (out pre-zeroed).
// ---------------------------------------------------------------------------
__global__ void wcomb_kernel(const float* __restrict__ Wsrc,
                             const float* __restrict__ W_attn,
                             const float* __restrict__ b_attn,
                             float* __restrict__ out, int nout) {
  int n = blockIdx.x * 256 + threadIdx.x;
  int k0 = blockIdx.y * 128;
  float a[27];
#pragma unroll
  for (int c = 0; c < 27; c++) a[c] = 0.f;
  for (int k = k0; k < k0 + 128; k++) {
    float wv = Wsrc[(size_t)k * nout + n];
#pragma unroll
    for (int i = 0; i < 3; i++) {
#pragma unroll
      for (int j = 0; j < 8; j++) a[i * 9 + j] += W_attn[(i * 8 + j) * 1024 + k] * wv;
      a[i * 9 + 8] += b_attn[i * 1024 + k] * wv;
    }
  }
#pragma unroll
  for (int c = 0; c < 27; c++) atomicAdd(&out[(size_t)c * nout + n], a[c]);
}

// ---------------------------------------------------------------------------
// GEMM: C[M,N] = A[M,K](bf16,rm) @ Bt[N,K](bf16,rm)^T + bias
// 128x128 tile, BK=64, 4 waves of 4x4 16x16x32 MFMA tiles.
// MODE 1: write bf16 C row-major (G).
// MODE 2: write fp32 + rank-27 correction: + sum_i (m_i[row]+bpinv)@Wo_i[:,col]
//         + Wo_i[8][col]  (final output projection)
// ---------------------------------------------------------------------------
template <int MODE>
__global__ __launch_bounds__(256, 3)
void gemm_bt(const bf16* __restrict__ A, const bf16* __restrict__ Bt,
             const float* __restrict__ bias, bf16* __restrict__ Gout,
             float* __restrict__ Cf, const float* __restrict__ mbuf,
             const float* __restrict__ bpinv, const float* __restrict__ Wo,
             int M, int N, int K) {
  __shared__ bf16 As[128 * 64];
  __shared__ bf16 Bs[128 * 64];
  const int t = threadIdx.x;
  const int w = t >> 6, lane = t & 63;
  const int lm = lane & 15, qd = lane >> 4;
  const int m0 = blockIdx.x * 128, n0 = blockIdx.y * 128;
  const int wm = (w & 1) * 64, wn = (w >> 1) * 64;

  const bf16* Ag = A + (size_t)m0 * K;
  const bf16* Bg = Bt + (size_t)n0 * K;

  f4v acc[4][4];
  f4v zero = {0.f, 0.f, 0.f, 0.f};
#pragma unroll
  for (int i = 0; i < 4; i++)
#pragma unroll
    for (int j = 0; j < 4; j++) acc[i][j] = zero;

  for (int k0 = 0; k0 < K; k0 += 64) {
#pragma unroll
    for (int c = 0; c < 4; c++) {
      int s = c * 256 + t;
      int r = s >> 3;
      int kc = (s & 7) ^ (r & 7);  // xor-swizzle: same 128B row, permuted 16B chunks
      gload16(Ag + (size_t)r * K + k0 + kc * 8, &As[s * 8]);
      gload16(Bg + (size_t)r * K + k0 + kc * 8, &Bs[s * 8]);
    }
    __syncthreads();
#pragma unroll
    for (int ks = 0; ks < 2; ks++) {
      b8 af[4], bfr[4];
#pragma unroll
      for (int tm = 0; tm < 4; tm++) {
        int row = wm + tm * 16 + lm;
        int ch = (ks * 4 + qd) ^ (row & 7);
        af[tm] = *(const b8*)&As[row * 64 + ch * 8];
      }
#pragma unroll
      for (int tn = 0; tn < 4; tn++) {
        int row = wn + tn * 16 + lm;
        int ch = (ks * 4 + qd) ^ (row & 7);
        bfr[tn] = *(const b8*)&Bs[row * 64 + ch * 8];
      }
#pragma unroll
      for (int tm = 0; tm < 4; tm++)
#pragma unroll
        for (int tn = 0; tn < 4; tn++)
          acc[tm][tn] = mfma_bf16(af[tm], bfr[tn], acc[tm][tn]);
    }
    __syncthreads();
  }

#pragma unroll
  for (int tn = 0; tn < 4; tn++) {
    int col = n0 + wn + tn * 16 + lm;
    float bv = bias[col];
    if (MODE == 1) {
#pragma unroll
      for (int tm = 0; tm < 4; tm++)
#pragma unroll
        for (int r = 0; r < 4; r++) {
          int row = m0 + wm + tm * 16 + qd * 4 + r;  // C layout: row=(lane>>4)*4+reg
          Gout[(size_t)row * N + col] = __float2bfloat16(acc[tm][tn][r] + bv);
        }
    } else {
      float woc[27];
#pragma unroll
      for (int i = 0; i < 3; i++)
#pragma unroll
        for (int j = 0; j < 9; j++)
          woc[i * 9 + j] = Wo[(size_t)(i * 9 + j) * 1024 + col];
      float bterm[3];
#pragma unroll
      for (int i = 0; i < 3; i++) {
        float s = woc[i * 9 + 8];
#pragma unroll
        for (int j = 0; j < 8; j++) s += bpinv[j] * woc[i * 9 + j];
        bterm[i] = s;
      }
#pragma unroll
      for (int tm = 0; tm < 4; tm++)
#pragma unroll
        for (int r = 0; r < 4; r++) {
          int row = m0 + wm + tm * 16 + qd * 4 + r;
          float add = acc[tm][tn][r] + bv;
#pragma unroll
          for (int i = 0; i < 3; i++) {
            const float* mi = mbuf + (size_t)i * 65536 + (size_t)row * 8;
            float4 ma = *(const float4*)mi;
            float4 mb = *(const float4*)(mi + 4);
            add += bterm[i] + ma.x * woc[i * 9 + 0] + ma.y * woc[i * 9 + 1] +
                   ma.z * woc[i * 9 + 2] + ma.w * woc[i * 9 + 3] +
                   mb.x * woc[i * 9 + 4] + mb.y * woc[i * 9 + 5] +
                   mb.z * woc[i * 9 + 6] + mb.w * woc[i * 9 + 7];
          }
          Cf[(size_t)row * N + col] = add;
        }
    }
  }
}

// ---------------------------------------------------------------------------
// corr<NL>: qkv_l = G + sum_{i<NL} (m_i+bpinv)@Wc_i + Wc_i[8]; then for part
// 0/1 (Q/K): fused expmap0 (+1/sqrt(128) for Q), write [B,H,S,HD]; part 2 (V):
// LDS-transpose (stride 66: odd word-stride => conflict-free b16 writes), then
// coalesced uint4 stores to Vt[bh][d][s].
// Block: 64 s-rows x 128 d-cols of one (part,head). Lane owns d=lane, lane+64.
// ---------------------------------------------------------------------------
template <int NL>
__global__ __launch_bounds__(256, 4)
void corr_kernel(const bf16* __restrict__ G, const float* __restrict__ mbuf,
                 const float* __restrict__ bpinv, const float* __restrict__ Wc,
                 bf16* __restrict__ Qo, bf16* __restrict__ Ko,
                 bf16* __restrict__ Vto) {
  __shared__ bf16 Gs[64 * 128];
  __shared__ bf16 VtT[128 * 66];
  const int t = threadIdx.x, w = t >> 6, lane = t & 63;
  const int ph = blockIdx.x;  // 0..23
  const int part = ph >> 3, h = ph & 7;
  const int sy = blockIdx.y;  // 0..127
  const int n0 = part * 1024 + h * 128;

#pragma unroll
  for (int c = 0; c < 4; c++) {
    int slot = c * 256 + t;
    int row = slot >> 4, ch = slot & 15;
    gload16(G + (size_t)(sy * 64 + row) * 3072 + n0 + ch * 8, &Gs[slot * 8]);
  }
  __syncthreads();

  float wca[NL > 0 ? NL : 1][9], wcb[NL > 0 ? NL : 1][9];
#pragma unroll
  for (int i = 0; i < NL; i++)
#pragma unroll
    for (int j = 0; j < 9; j++) {
      wca[i][j] = Wc[(size_t)(i * 9 + j) * 3072 + n0 + lane];
      wcb[i][j] = Wc[(size_t)(i * 9 + j) * 3072 + n0 + lane + 64];
    }
  const float qsc = (part == 0) ? 0.08838834764831845f : 1.0f;  // 1/sqrt(128)
  bf16* dst = (part == 0) ? Qo : Ko;

  for (int rr = 0; rr < 16; rr++) {
    int row = w * 16 + rr;
    int s = sy * 64 + row;
    float g0 = __bfloat162float(Gs[row * 128 + lane]);
    float g1 = __bfloat162float(Gs[row * 128 + lane + 64]);
#pragma unroll
    for (int i = 0; i < NL; i++) {
      const float* mi = mbuf + (size_t)i * 65536 + (size_t)s * 8;
      float4 ma = *(const float4*)mi;
      float4 mb = *(const float4*)(mi + 4);
      float a0 = ma.x + bpinv[0], a1 = ma.y + bpinv[1];
      float a2 = ma.z + bpinv[2], a3 = ma.w + bpinv[3];
      float a4 = mb.x + bpinv[4], a5 = mb.y + bpinv[5];
      float a6 = mb.z + bpinv[6], a7 = mb.w + bpinv[7];
      g0 += a0 * wca[i][0] + a1 * wca[i][1] + a2 * wca[i][2] + a3 * wca[i][3] +
            a4 * wca[i][4] + a5 * wca[i][5] + a6 * wca[i][6] + a7 * wca[i][7] +
            wca[i][8];
      g1 += a0 * wcb[i][0] + a1 * wcb[i][1] + a2 * wcb[i][2] + a3 * wcb[i][3] +
            a4 * wcb[i][4] + a5 * wcb[i][5] + a6 * wcb[i][6] + a7 * wcb[i][7] +
            wcb[i][8];
    }
    if (part < 2) {
      float ss = g0 * g0 + g1 * g1;
#pragma unroll
      for (int off = 32; off; off >>= 1) ss += __shfl_xor(ss, off, 64);
      float n = fmaxf(sqrtf(ss), 1e-7f);
      float sc = tanhf(n) / n * qsc;
      int b = s >> 10, sIdx = s & 1023;
      bf16* drow = dst + (((size_t)(b * 8 + h)) * 1024 + sIdx) * 128;
      drow[lane] = __float2bfloat16(g0 * sc);
      drow[lane + 64] = __float2bfloat16(g1 * sc);
    } else {
      VtT[lane * 66 + row] = __float2bfloat16(g0);
      VtT[(lane + 64) * 66 + row] = __float2bfloat16(g1);
    }
  }
  if (part == 2) {
    __syncthreads();
    int d = t >> 1, half = t & 1;
    int s0g = sy * 64;
    int b = s0g >> 10, sIdx0 = s0g & 1023;
    bf16* orow = Vto + ((size_t)(b * 8 + h)) * 131072 + (size_t)d * 1024 + sIdx0 +
                 half * 32;
#pragma unroll
    for (int i = 0; i < 4; i++) {
      uint32_t u[4];
#pragma unroll
      for (int c = 0; c < 4; c++)
        u[c] = *(const uint32_t*)&VtT[d * 66 + half * 32 + i * 8 + c * 2];
      uint4 pk = make_uint4(u[0], u[1], u[2], u[3]);
      *(uint4*)&orow[i * 8] = pk;
    }
  }
}

// ---------------------------------------------------------------------------
// Flash attention, no-max softmax (|score| <= 1/sqrt(128); exp in [0.915,1.092]).
// l via MFMA against all-ones B. grid (64 bh, 8 qt) => same-bh same-XCD.
// 4 waves x 32 q-rows; K-fragments shared across both m-tiles.
// Epilogue: m_partial[s][j] += sum_d o_norm[s][d]*W_pinv[h*128+d][j] via
// quad-shfl reduce + atomicAdd (O is never materialized).
// ---------------------------------------------------------------------------
__global__ __launch_bounds__(256, 2)
void attn_kernel(const bf16* __restrict__ Qf, const bf16* __restrict__ Kf,
                 const bf16* __restrict__ Vt, const float* __restrict__ Wpinv,
                 float* __restrict__ mbuf) {
  __shared__ bf16 smem[24576];            // 49152 B
  bf16* Ks = smem;                        // [64 s'][128 d] chunk-swizzled
  bf16* Vs = smem + 8192;                 // [128 d][64 s'] chunk-swizzled
  bf16* Ps = smem + 16384;                // [4 waves][32 q][64 s'] perm-swizzled
  const int t = threadIdx.x, w = t >> 6, lane = t & 63;
  const int lm = lane & 15, qd = lane >> 4;
  const int bh = blockIdx.x, qt = blockIdx.y;
  const bf16* Qg = Qf + ((size_t)bh * 1024 + qt * 128) * 128;
  const bf16* Kg = Kf + (size_t)bh * 131072;
  const bf16* Vg = Vt + (size_t)bh * 131072;
  bf16* Pw = Ps + w * 2048;

  b8 qfr[2][4];
#pragma unroll
  for (int mt = 0; mt < 2; mt++)
#pragma unroll
    for (int ks = 0; ks < 4; ks++)
      qfr[mt][ks] =
          *(const b8*)(Qg + (size_t)(w * 32 + mt * 16 + lm) * 128 + ks * 32 + qd * 8);

  f4v o[2][8];
  f4v lacc[2];
  f4v zero = {0.f, 0.f, 0.f, 0.f};
#pragma unroll
  for (int mt = 0; mt < 2; mt++) {
    lacc[mt] = zero;
#pragma unroll
    for (int i = 0; i < 8; i++) o[mt][i] = zero;
  }
  union { s8v s; b8 b; } uo;
#pragma unroll
  for (int i = 0; i < 8; i++) uo.s[i] = 0x3F80;  // bf16 1.0
  const b8 ones = uo.b;

  for (int kt = 0; kt < 16; kt++) {
    __syncthreads();
#pragma unroll
    for (int c = 0; c < 4; c++) {
      int s = c * 256 + t;
      int r = s >> 4;
      int kc = (s & 15) ^ (r & 7);
      gload16(Kg + (size_t)(kt * 64 + r) * 128 + kc * 8, &Ks[s * 8]);
      int rv = s >> 3;
      int kv = (s & 7) ^ (rv & 7);
      gload16(Vg + (size_t)rv * 1024 + kt * 64 + kv * 8, &Vs[s * 8]);
    }
    __syncthreads();

    f4v sc[2][4];
#pragma unroll
    for (int mt = 0; mt < 2; mt++)
#pragma unroll
      for (int tn = 0; tn < 4; tn++) sc[mt][tn] = zero;
#pragma unroll
    for (int tn = 0; tn < 4; tn++) {
      int krow = tn * 16 + lm;
#pragma unroll
      for (int ks = 0; ks < 4; ks++) {
        int ch = (ks * 4 + qd) ^ (krow & 7);
        b8 kfr = *(const b8*)&Ks[krow * 128 + ch * 8];
        sc[0][tn] = mfma_bf16(qfr[0][ks], kfr, sc[0][tn]);
        sc[1][tn] = mfma_bf16(qfr[1][ks], kfr, sc[1][tn]);
      }
    }
#pragma unroll
    for (int mt = 0; mt < 2; mt++)
#pragma unroll
      for (int tn = 0; tn < 4; tn++)
#pragma unroll
        for (int r = 0; r < 4; r++) {
          int qi = mt * 16 + qd * 4 + r;
          int ch = (tn * 2 + (lm >> 3)) ^ ((qi >> 1) & 7);
          Pw[qi * 64 + ch * 8 + (lm & 7)] = __float2bfloat16(__expf(sc[mt][tn][r]));
        }

    b8 pa[2][2];
#pragma unroll
    for (int mt = 0; mt < 2; mt++)
#pragma unroll
      for (int kv2 = 0; kv2 < 2; kv2++) {
        int qi = mt * 16 + lm;
        int ch = (kv2 * 4 + qd) ^ ((lm >> 1) & 7);
        pa[mt][kv2] = *(const b8*)&Pw[qi * 64 + ch * 8];
      }
#pragma unroll
    for (int mt = 0; mt < 2; mt++)
#pragma unroll
      for (int kv2 = 0; kv2 < 2; kv2++)
        lacc[mt] = mfma_bf16(pa[mt][kv2], ones, lacc[mt]);
#pragma unroll
    for (int tnd = 0; tnd < 8; tnd++) {
      int drow = tnd * 16 + lm;
#pragma unroll
      for (int kv2 = 0; kv2 < 2; kv2++) {
        int ch = (kv2 * 4 + qd) ^ (drow & 7);
        b8 vfr = *(const b8*)&Vs[drow * 64 + ch * 8];
#pragma unroll
        for (int mt = 0; mt < 2; mt++)
          o[mt][tnd] = mfma_bf16(pa[mt][kv2], vfr, o[mt][tnd]);
      }
    }
  }

  // epilogue: project o (normalized) onto W_pinv -> atomic m partials
  const int b = bh >> 3, h = bh & 7;
#pragma unroll
  for (int mt = 0; mt < 2; mt++) {
    float rinv[4];
#pragma unroll
    for (int r = 0; r < 4; r++) rinv[r] = 1.0f / lacc[mt][r];
    float msum[4][8];
#pragma unroll
    for (int r = 0; r < 4; r++)
#pragma unroll
      for (int j = 0; j < 8; j++) msum[r][j] = 0.f;
#pragma unroll
    for (int tnd = 0; tnd < 8; tnd++) {
      int d = tnd * 16 + lm;
      const float* wp = Wpinv + (size_t)(h * 128 + d) * 8;
      float4 wa = *(const float4*)wp;
      float4 wb = *(const float4*)(wp + 4);
#pragma unroll
      for (int r = 0; r < 4; r++) {
        float on = o[mt][tnd][r] * rinv[r];
        msum[r][0] += on * wa.x; msum[r][1] += on * wa.y;
        msum[r][2] += on * wa.z; msum[r][3] += on * wa.w;
        msum[r][4] += on * wb.x; msum[r][5] += on * wb.y;
        msum[r][6] += on * wb.z; msum[r][7] += on * wb.w;
      }
    }
#pragma unroll
    for (int r = 0; r < 4; r++)
#pragma unroll
      for (int j = 0; j < 8; j++)
#pragma unroll
        for (int off = 1; off < 16; off <<= 1)
          msum[r][j] += __shfl_xor(msum[r][j], off, 64);
    if (lm == 0) {
#pragma unroll
      for (int r = 0; r < 4; r++) {
        int sIdx = qt * 128 + w * 32 + mt * 16 + qd * 4 + r;
        float* md = mbuf + ((size_t)b * 1024 + sIdx) * 8;
#pragma unroll
        for (int j = 0; j < 8; j++) atomicAdd(&md[j], msum[r][j]);
      }
    }
  }
}

// ---------------------------------------------------------------------------
extern "C" void kernel_launch(void* const* d_in, const int* in_sizes, int n_in,
                              void* d_out, int out_size, void* d_ws, size_t ws_size,
                              hipStream_t stream) {
  const float* x      = (const float*)d_in[0];
  const float* W_qkv  = (const float*)d_in[1];
  const float* b_qkv  = (const float*)d_in[2];
  const float* W_pinv = (const float*)d_in[3];
  const float* b_pinv = (const float*)d_in[4];
  const float* W_attn = (const float*)d_in[5];
  const float* b_attn = (const float*)d_in[6];
  const float* W_out  = (const float*)d_in[7];
  const float* b_out  = (const float*)d_in[8];

  char* ws = (char*)d_ws;
  size_t off = 0;
  auto alloc = [&](size_t bytes) -> void* {
    void* p = ws + off;
    off += (bytes + 255) & ~(size_t)255;
    return p;
  };
  // zero-region: m(3x65536) Wc(27x3072) Wo(27x1024) MUST be contiguous
  float* mz    = (float*)alloc((size_t)307200 * 4);          // 1.2MB
  float* mbuf  = mz;                                         // 3 x 8192 x 8
  float* Wc    = mz + 196608;                                // 27 x 3072
  float* Wo    = mz + 196608 + 82944;                        // 27 x 1024
  bf16* xb     = (bf16*)alloc((size_t)8192 * 1024 * 2);      // 16MB
  bf16* Wqkvt  = (bf16*)alloc((size_t)3072 * 1024 * 2);      // 6MB [3072][1024]
  bf16* Woutt  = (bf16*)alloc((size_t)1024 * 1024 * 2);      // 2MB
  bf16* G      = (bf16*)alloc((size_t)8192 * 3072 * 2);      // 48MB [8192][3072]
  bf16* Q      = (bf16*)alloc((size_t)8192 * 1024 * 2);      // 16MB [B,H,S,HD] flowed
  bf16* Kt     = (bf16*)alloc((size_t)8192 * 1024 * 2);      // 16MB [B,H,S,HD] flowed
  bf16* Vt     = (bf16*)alloc((size_t)8192 * 1024 * 2);      // 16MB [B,H,HD,S]
  (void)ws_size; (void)in_sizes; (void)n_in; (void)out_size;

  prep_kernel<<<8192, 256, 0, stream>>>(x, xb, mz);
  transpose_cast<<<dim3(96, 32), 256, 0, stream>>>(W_qkv, Wqkvt, 1024, 3072);
  transpose_cast<<<dim3(32, 32), 256, 0, stream>>>(W_out, Woutt, 1024, 1024);
  wcomb_kernel<<<dim3(12, 8), 256, 0, stream>>>(W_qkv, W_attn, b_attn, Wc, 3072);
  wcomb_kernel<<<dim3(4, 8), 256, 0, stream>>>(W_out, W_attn, b_attn, Wo, 1024);

  // G = x @ W_qkv + b_qkv  (the ONLY large qkv GEMM)
  gemm_bt<1><<<dim3(64, 24), 256, 0, stream>>>(xb, Wqkvt, b_qkv, G, nullptr,
                                               nullptr, nullptr, nullptr,
                                               8192, 3072, 1024);
  // layer 0
  corr_kernel<0><<<dim3(24, 128), 256, 0, stream>>>(G, mbuf, b_pinv, Wc, Q, Kt, Vt);
  attn_kernel<<<dim3(64, 8), 256, 0, stream>>>(Q, Kt, Vt, W_pinv, mbuf);
  // layer 1
  corr_kernel<1><<<dim3(24, 128), 256, 0, stream>>>(G, mbuf, b_pinv, Wc, Q, Kt, Vt);
  attn_kernel<<<dim3(64, 8), 256, 0, stream>>>(Q, Kt, Vt, W_pinv, mbuf + 65536);
  // layer 2
  corr_kernel<2><<<dim3(24, 128), 256, 0, stream>>>(G, mbuf, b_pinv, Wc, Q, Kt, Vt);
  attn_kernel<<<dim3(64, 8), 256, 0, stream>>>(Q, Kt, Vt, W_pinv, mbuf + 131072);
  // out = x @ W_out + b_out + sum_i (m_i + b_pinv) @ Wo_i  (rank-27 epilogue)
  gemm_bt<2><<<dim3(64, 8), 256, 0, stream>>>(xb, Woutt, b_out, nullptr,
                                              (float*)d_out, mbuf, b_pinv, Wo,
                                              8192, 1024, 1024);
}

// Round 6
// 707.033 us; speedup vs baseline: 1.8635x; 1.8635x over previous
//
#include <hip/hip_runtime.h>
#include <hip/hip_bf16.h>
#include <cstdint>

typedef __hip_bfloat16 bf16;
typedef __bf16 b8 __attribute__((ext_vector_type(8)));
typedef float f4v __attribute__((ext_vector_type(4)));
typedef short s8v __attribute__((ext_vector_type(8)));

#define DEVI static __device__ __forceinline__

// async global->LDS, 16B per lane. LDS dest is wave-uniform base + lane*16.
DEVI void gload16(const void* g, void* l) {
  __builtin_amdgcn_global_load_lds(
      (const __attribute__((address_space(1))) void*)(uintptr_t)g,
      (__attribute__((address_space(3))) void*)(uint32_t)(uintptr_t)l,
      16, 0, 0);
}

DEVI f4v mfma_bf16(b8 a, b8 b, f4v c) {
  return __builtin_amdgcn_mfma_f32_16x16x32_bf16(a, b, c, 0, 0, 0);
}

// ---------------------------------------------------------------------------
// prep: x -> xb (bf16); zero m (3x8192x8) + Wc (27x3072) + Wo (27x1024) region
// ---------------------------------------------------------------------------
__global__ void prep_kernel(const float* __restrict__ x, bf16* __restrict__ xb,
                            float* __restrict__ zbase) {
  int gid = blockIdx.x * 256 + threadIdx.x;
  int i = gid * 4;
  float4 v = *(const float4*)(x + i);
  __hip_bfloat162 a, b;
  a.x = __float2bfloat16(v.x); a.y = __float2bfloat16(v.y);
  b.x = __float2bfloat16(v.z); b.y = __float2bfloat16(v.w);
  *(__hip_bfloat162*)(xb + i) = a;
  *(__hip_bfloat162*)(xb + i + 2) = b;
  if (gid < 307200) zbase[gid] = 0.f;  // 196608 m + 82944 Wc + 27648 Wo
}

// ---------------------------------------------------------------------------
// transpose + cast fp32 [R][C] -> bf16 [C][R]   (weights, tiny)
// ---------------------------------------------------------------------------
__global__ void transpose_cast(const float* __restrict__ in, bf16* __restrict__ out,
                               int R, int C) {
  __shared__ float tile[32][33];
  int c0 = blockIdx.x * 32, r0 = blockIdx.y * 32;
  int tx = threadIdx.x & 31, ty = threadIdx.x >> 5;  // 32 x 8
  for (int rr = ty; rr < 32; rr += 8)
    tile[rr][tx] = in[(size_t)(r0 + rr) * C + c0 + tx];
  __syncthreads();
  for (int cc = ty; cc < 32; cc += 8)
    out[(size_t)(c0 + cc) * R + r0 + tx] = __float2bfloat16(tile[tx][cc]);
}

// ---------------------------------------------------------------------------
// wcomb: out[i*9+j][n] = sum_k row(i,j)[k] * Wsrc[k][n]; row j<8 = W_attn[i][j],
// j=8 = b_attn[i]. k split into 8 chunks, atomicAdd (out pre-zeroed).
// ---------------------------------------------------------------------------
__global__ void wcomb_kernel(const float* __restrict__ Wsrc,
                             const float* __restrict__ W_attn,
                             const float* __restrict__ b_attn,
                             float* __restrict__ out, int nout) {
  int n = blockIdx.x * 256 + threadIdx.x;
  int k0 = blockIdx.y * 128;
  float a[27];
#pragma unroll
  for (int c = 0; c < 27; c++) a[c] = 0.f;
  for (int k = k0; k < k0 + 128; k++) {
    float wv = Wsrc[(size_t)k * nout + n];
#pragma unroll
    for (int i = 0; i < 3; i++) {
#pragma unroll
      for (int j = 0; j < 8; j++) a[i * 9 + j] += W_attn[(i * 8 + j) * 1024 + k] * wv;
      a[i * 9 + 8] += b_attn[i * 1024 + k] * wv;
    }
  }
#pragma unroll
  for (int c = 0; c < 27; c++) atomicAdd(&out[(size_t)c * nout + n], a[c]);
}

// ---------------------------------------------------------------------------
// GEMM: C[M,N] = A[M,K](bf16,rm) @ Bt[N,K](bf16,rm)^T + bias
// 128x128 tile, BK=64, 4 waves of 4x4 16x16x32 MFMA tiles. Register-light
// epilogues ONLY (acc stays in AGPRs; no heavy fused math -> no spill).
// MODE 0: write fp32 C row-major.  MODE 1: write bf16 C row-major (G).
// ---------------------------------------------------------------------------
template <int MODE>
__global__ __launch_bounds__(256, 3)
void gemm_bt(const bf16* __restrict__ A, const bf16* __restrict__ Bt,
             const float* __restrict__ bias, bf16* __restrict__ Gout,
             float* __restrict__ Cf, int M, int N, int K) {
  __shared__ bf16 As[128 * 64];
  __shared__ bf16 Bs[128 * 64];
  const int t = threadIdx.x;
  const int w = t >> 6, lane = t & 63;
  const int lm = lane & 15, qd = lane >> 4;
  const int m0 = blockIdx.x * 128, n0 = blockIdx.y * 128;
  const int wm = (w & 1) * 64, wn = (w >> 1) * 64;

  const bf16* Ag = A + (size_t)m0 * K;
  const bf16* Bg = Bt + (size_t)n0 * K;

  f4v acc[4][4];
  f4v zero = {0.f, 0.f, 0.f, 0.f};
#pragma unroll
  for (int i = 0; i < 4; i++)
#pragma unroll
    for (int j = 0; j < 4; j++) acc[i][j] = zero;

  for (int k0 = 0; k0 < K; k0 += 64) {
#pragma unroll
    for (int c = 0; c < 4; c++) {
      int s = c * 256 + t;
      int r = s >> 3;
      int kc = (s & 7) ^ (r & 7);  // xor-swizzle: same 128B row, permuted 16B chunks
      gload16(Ag + (size_t)r * K + k0 + kc * 8, &As[s * 8]);
      gload16(Bg + (size_t)r * K + k0 + kc * 8, &Bs[s * 8]);
    }
    __syncthreads();
#pragma unroll
    for (int ks = 0; ks < 2; ks++) {
      b8 af[4], bfr[4];
#pragma unroll
      for (int tm = 0; tm < 4; tm++) {
        int row = wm + tm * 16 + lm;
        int ch = (ks * 4 + qd) ^ (row & 7);
        af[tm] = *(const b8*)&As[row * 64 + ch * 8];
      }
#pragma unroll
      for (int tn = 0; tn < 4; tn++) {
        int row = wn + tn * 16 + lm;
        int ch = (ks * 4 + qd) ^ (row & 7);
        bfr[tn] = *(const b8*)&Bs[row * 64 + ch * 8];
      }
#pragma unroll
      for (int tm = 0; tm < 4; tm++)
#pragma unroll
        for (int tn = 0; tn < 4; tn++)
          acc[tm][tn] = mfma_bf16(af[tm], bfr[tn], acc[tm][tn]);
    }
    __syncthreads();
  }

#pragma unroll
  for (int tn = 0; tn < 4; tn++) {
    int col = n0 + wn + tn * 16 + lm;
    float bv = bias[col];
#pragma unroll
    for (int tm = 0; tm < 4; tm++)
#pragma unroll
      for (int r = 0; r < 4; r++) {
        int row = m0 + wm + tm * 16 + qd * 4 + r;  // C layout: row=(lane>>4)*4+reg
        if (MODE == 1)
          Gout[(size_t)row * N + col] = __float2bfloat16(acc[tm][tn][r] + bv);
        else
          Cf[(size_t)row * N + col] = acc[tm][tn][r] + bv;
      }
  }
}

// ---------------------------------------------------------------------------
// outcorr: out[row][col] += sum_i ((m_i[row]+bpinv) @ Wo_i[:,col] + Wo_i[8][col])
// Pure memory-bound RMW (32MB read + 32MB write); weights L2-cached.
// ---------------------------------------------------------------------------
__global__ __launch_bounds__(256)
void outcorr_kernel(float* __restrict__ out, const float* __restrict__ mbuf,
                    const float* __restrict__ bpinv, const float* __restrict__ Wo) {
  const int row = blockIdx.x;
  const int h0 = threadIdx.x * 4;
  __shared__ float sm[24];
  if (threadIdx.x < 24) {
    int i = threadIdx.x >> 3, j = threadIdx.x & 7;
    sm[threadIdx.x] = mbuf[(size_t)i * 65536 + (size_t)row * 8 + j] + bpinv[j];
  }
  __syncthreads();
  float u[4] = {0.f, 0.f, 0.f, 0.f};
#pragma unroll
  for (int i = 0; i < 3; i++)
#pragma unroll
    for (int j = 0; j < 9; j++) {
      float4 wv = *(const float4*)(Wo + (size_t)(i * 9 + j) * 1024 + h0);
      float mj = (j < 8) ? sm[i * 8 + j] : 1.0f;
      u[0] += mj * wv.x; u[1] += mj * wv.y; u[2] += mj * wv.z; u[3] += mj * wv.w;
    }
  float4 c4 = *(float4*)(out + (size_t)row * 1024 + h0);
  c4.x += u[0]; c4.y += u[1]; c4.z += u[2]; c4.w += u[3];
  *(float4*)(out + (size_t)row * 1024 + h0) = c4;
}

// ---------------------------------------------------------------------------
// corr<NL>: qkv_l = G + sum_{i<NL} (m_i+bpinv)@Wc_i + Wc_i[8]; then for part
// 0/1 (Q/K): fused expmap0 (+1/sqrt(128) for Q), write [B,H,S,HD]; part 2 (V):
// LDS-transpose (stride 66), coalesced uint4 stores to Vt[bh][d][s].
// Block: 64 s-rows x 128 d-cols of one (part,head). Lane owns d=lane, lane+64.
// ---------------------------------------------------------------------------
template <int NL>
__global__ __launch_bounds__(256, 4)
void corr_kernel(const bf16* __restrict__ G, const float* __restrict__ mbuf,
                 const float* __restrict__ bpinv, const float* __restrict__ Wc,
                 bf16* __restrict__ Qo, bf16* __restrict__ Ko,
                 bf16* __restrict__ Vto) {
  __shared__ bf16 Gs[64 * 128];
  __shared__ bf16 VtT[128 * 66];
  const int t = threadIdx.x, w = t >> 6, lane = t & 63;
  const int ph = blockIdx.x;  // 0..23
  const int part = ph >> 3, h = ph & 7;
  const int sy = blockIdx.y;  // 0..127
  const int n0 = part * 1024 + h * 128;

#pragma unroll
  for (int c = 0; c < 4; c++) {
    int slot = c * 256 + t;
    int row = slot >> 4, ch = slot & 15;
    gload16(G + (size_t)(sy * 64 + row) * 3072 + n0 + ch * 8, &Gs[slot * 8]);
  }
  __syncthreads();

  float wca[NL > 0 ? NL : 1][9], wcb[NL > 0 ? NL : 1][9];
#pragma unroll
  for (int i = 0; i < NL; i++)
#pragma unroll
    for (int j = 0; j < 9; j++) {
      wca[i][j] = Wc[(size_t)(i * 9 + j) * 3072 + n0 + lane];
      wcb[i][j] = Wc[(size_t)(i * 9 + j) * 3072 + n0 + lane + 64];
    }
  const float qsc = (part == 0) ? 0.08838834764831845f : 1.0f;  // 1/sqrt(128)
  bf16* dst = (part == 0) ? Qo : Ko;

  for (int rr = 0; rr < 16; rr++) {
    int row = w * 16 + rr;
    int s = sy * 64 + row;
    float g0 = __bfloat162float(Gs[row * 128 + lane]);
    float g1 = __bfloat162float(Gs[row * 128 + lane + 64]);
#pragma unroll
    for (int i = 0; i < NL; i++) {
      const float* mi = mbuf + (size_t)i * 65536 + (size_t)s * 8;
      float4 ma = *(const float4*)mi;
      float4 mb = *(const float4*)(mi + 4);
      float a0 = ma.x + bpinv[0], a1 = ma.y + bpinv[1];
      float a2 = ma.z + bpinv[2], a3 = ma.w + bpinv[3];
      float a4 = mb.x + bpinv[4], a5 = mb.y + bpinv[5];
      float a6 = mb.z + bpinv[6], a7 = mb.w + bpinv[7];
      g0 += a0 * wca[i][0] + a1 * wca[i][1] + a2 * wca[i][2] + a3 * wca[i][3] +
            a4 * wca[i][4] + a5 * wca[i][5] + a6 * wca[i][6] + a7 * wca[i][7] +
            wca[i][8];
      g1 += a0 * wcb[i][0] + a1 * wcb[i][1] + a2 * wcb[i][2] + a3 * wcb[i][3] +
            a4 * wcb[i][4] + a5 * wcb[i][5] + a6 * wcb[i][6] + a7 * wcb[i][7] +
            wcb[i][8];
    }
    if (part < 2) {
      float ss = g0 * g0 + g1 * g1;
#pragma unroll
      for (int off = 32; off; off >>= 1) ss += __shfl_xor(ss, off, 64);
      float n = fmaxf(sqrtf(ss), 1e-7f);
      float sc = tanhf(n) / n * qsc;
      int b = s >> 10, sIdx = s & 1023;
      bf16* drow = dst + (((size_t)(b * 8 + h)) * 1024 + sIdx) * 128;
      drow[lane] = __float2bfloat16(g0 * sc);
      drow[lane + 64] = __float2bfloat16(g1 * sc);
    } else {
      VtT[lane * 66 + row] = __float2bfloat16(g0);
      VtT[(lane + 64) * 66 + row] = __float2bfloat16(g1);
    }
  }
  if (part == 2) {
    __syncthreads();
    int d = t >> 1, half = t & 1;
    int s0g = sy * 64;
    int b = s0g >> 10, sIdx0 = s0g & 1023;
    bf16* orow = Vto + ((size_t)(b * 8 + h)) * 131072 + (size_t)d * 1024 + sIdx0 +
                 half * 32;
#pragma unroll
    for (int i = 0; i < 4; i++) {
      uint32_t u[4];
#pragma unroll
      for (int c = 0; c < 4; c++)
        u[c] = *(const uint32_t*)&VtT[d * 66 + half * 32 + i * 8 + c * 2];
      uint4 pk = make_uint4(u[0], u[1], u[2], u[3]);
      *(uint4*)&orow[i * 8] = pk;
    }
  }
}

// ---------------------------------------------------------------------------
// Flash attention, no-max softmax (|score| <= 1/sqrt(128); exp in [0.915,1.092]).
// l via MFMA against all-ones B. grid (64 bh, 8 qt) => same-bh same-XCD.
// 4 waves x 32 q-rows; K-fragments shared across both m-tiles.
// Epilogue: m_partial[s][j] += sum_d o_norm[s][d]*W_pinv[h*128+d][j] via
// quad-shfl reduce + atomicAdd (O is never materialized).
// ---------------------------------------------------------------------------
__global__ __launch_bounds__(256, 2)
void attn_kernel(const bf16* __restrict__ Qf, const bf16* __restrict__ Kf,
                 const bf16* __restrict__ Vt, const float* __restrict__ Wpinv,
                 float* __restrict__ mbuf) {
  __shared__ bf16 smem[24576];            // 49152 B
  bf16* Ks = smem;                        // [64 s'][128 d] chunk-swizzled
  bf16* Vs = smem + 8192;                 // [128 d][64 s'] chunk-swizzled
  bf16* Ps = smem + 16384;                // [4 waves][32 q][64 s'] perm-swizzled
  const int t = threadIdx.x, w = t >> 6, lane = t & 63;
  const int lm = lane & 15, qd = lane >> 4;
  const int bh = blockIdx.x, qt = blockIdx.y;
  const bf16* Qg = Qf + ((size_t)bh * 1024 + qt * 128) * 128;
  const bf16* Kg = Kf + (size_t)bh * 131072;
  const bf16* Vg = Vt + (size_t)bh * 131072;
  bf16* Pw = Ps + w * 2048;

  b8 qfr[2][4];
#pragma unroll
  for (int mt = 0; mt < 2; mt++)
#pragma unroll
    for (int ks = 0; ks < 4; ks++)
      qfr[mt][ks] =
          *(const b8*)(Qg + (size_t)(w * 32 + mt * 16 + lm) * 128 + ks * 32 + qd * 8);

  f4v o[2][8];
  f4v lacc[2];
  f4v zero = {0.f, 0.f, 0.f, 0.f};
#pragma unroll
  for (int mt = 0; mt < 2; mt++) {
    lacc[mt] = zero;
#pragma unroll
    for (int i = 0; i < 8; i++) o[mt][i] = zero;
  }
  union { s8v s; b8 b; } uo;
#pragma unroll
  for (int i = 0; i < 8; i++) uo.s[i] = 0x3F80;  // bf16 1.0
  const b8 ones = uo.b;

  for (int kt = 0; kt < 16; kt++) {
    __syncthreads();
#pragma unroll
    for (int c = 0; c < 4; c++) {
      int s = c * 256 + t;
      int r = s >> 4;
      int kc = (s & 15) ^ (r & 7);
      gload16(Kg + (size_t)(kt * 64 + r) * 128 + kc * 8, &Ks[s * 8]);
      int rv = s >> 3;
      int kv = (s & 7) ^ (rv & 7);
      gload16(Vg + (size_t)rv * 1024 + kt * 64 + kv * 8, &Vs[s * 8]);
    }
    __syncthreads();

    f4v sc[2][4];
#pragma unroll
    for (int mt = 0; mt < 2; mt++)
#pragma unroll
      for (int tn = 0; tn < 4; tn++) sc[mt][tn] = zero;
#pragma unroll
    for (int tn = 0; tn < 4; tn++) {
      int krow = tn * 16 + lm;
#pragma unroll
      for (int ks = 0; ks < 4; ks++) {
        int ch = (ks * 4 + qd) ^ (krow & 7);
        b8 kfr = *(const b8*)&Ks[krow * 128 + ch * 8];
        sc[0][tn] = mfma_bf16(qfr[0][ks], kfr, sc[0][tn]);
        sc[1][tn] = mfma_bf16(qfr[1][ks], kfr, sc[1][tn]);
      }
    }
#pragma unroll
    for (int mt = 0; mt < 2; mt++)
#pragma unroll
      for (int tn = 0; tn < 4; tn++)
#pragma unroll
        for (int r = 0; r < 4; r++) {
          int qi = mt * 16 + qd * 4 + r;
          int ch = (tn * 2 + (lm >> 3)) ^ ((qi >> 1) & 7);
          Pw[qi * 64 + ch * 8 + (lm & 7)] = __float2bfloat16(__expf(sc[mt][tn][r]));
        }

    b8 pa[2][2];
#pragma unroll
    for (int mt = 0; mt < 2; mt++)
#pragma unroll
      for (int kv2 = 0; kv2 < 2; kv2++) {
        int qi = mt * 16 + lm;
        int ch = (kv2 * 4 + qd) ^ ((lm >> 1) & 7);
        pa[mt][kv2] = *(const b8*)&Pw[qi * 64 + ch * 8];
      }
#pragma unroll
    for (int mt = 0; mt < 2; mt++)
#pragma unroll
      for (int kv2 = 0; kv2 < 2; kv2++)
        lacc[mt] = mfma_bf16(pa[mt][kv2], ones, lacc[mt]);
#pragma unroll
    for (int tnd = 0; tnd < 8; tnd++) {
      int drow = tnd * 16 + lm;
#pragma unroll
      for (int kv2 = 0; kv2 < 2; kv2++) {
        int ch = (kv2 * 4 + qd) ^ (drow & 7);
        b8 vfr = *(const b8*)&Vs[drow * 64 + ch * 8];
#pragma unroll
        for (int mt = 0; mt < 2; mt++)
          o[mt][tnd] = mfma_bf16(pa[mt][kv2], vfr, o[mt][tnd]);
      }
    }
  }

  // epilogue: project o (normalized) onto W_pinv -> atomic m partials
  const int b = bh >> 3, h = bh & 7;
#pragma unroll
  for (int mt = 0; mt < 2; mt++) {
    float rinv[4];
#pragma unroll
    for (int r = 0; r < 4; r++) rinv[r] = 1.0f / lacc[mt][r];
    float msum[4][8];
#pragma unroll
    for (int r = 0; r < 4; r++)
#pragma unroll
      for (int j = 0; j < 8; j++) msum[r][j] = 0.f;
#pragma unroll
    for (int tnd = 0; tnd < 8; tnd++) {
      int d = tnd * 16 + lm;
      const float* wp = Wpinv + (size_t)(h * 128 + d) * 8;
      float4 wa = *(const float4*)wp;
      float4 wb = *(const float4*)(wp + 4);
#pragma unroll
      for (int r = 0; r < 4; r++) {
        float on = o[mt][tnd][r] * rinv[r];
        msum[r][0] += on * wa.x; msum[r][1] += on * wa.y;
        msum[r][2] += on * wa.z; msum[r][3] += on * wa.w;
        msum[r][4] += on * wb.x; msum[r][5] += on * wb.y;
        msum[r][6] += on * wb.z; msum[r][7] += on * wb.w;
      }
    }
#pragma unroll
    for (int r = 0; r < 4; r++)
#pragma unroll
      for (int j = 0; j < 8; j++)
#pragma unroll
        for (int off = 1; off < 16; off <<= 1)
          msum[r][j] += __shfl_xor(msum[r][j], off, 64);
    if (lm == 0) {
#pragma unroll
      for (int r = 0; r < 4; r++) {
        int sIdx = qt * 128 + w * 32 + mt * 16 + qd * 4 + r;
        float* md = mbuf + ((size_t)b * 1024 + sIdx) * 8;
#pragma unroll
        for (int j = 0; j < 8; j++) atomicAdd(&md[j], msum[r][j]);
      }
    }
  }
}

// ---------------------------------------------------------------------------
extern "C" void kernel_launch(void* const* d_in, const int* in_sizes, int n_in,
                              void* d_out, int out_size, void* d_ws, size_t ws_size,
                              hipStream_t stream) {
  const float* x      = (const float*)d_in[0];
  const float* W_qkv  = (const float*)d_in[1];
  const float* b_qkv  = (const float*)d_in[2];
  const float* W_pinv = (const float*)d_in[3];
  const float* b_pinv = (const float*)d_in[4];
  const float* W_attn = (const float*)d_in[5];
  const float* b_attn = (const float*)d_in[6];
  const float* W_out  = (const float*)d_in[7];
  const float* b_out  = (const float*)d_in[8];

  char* ws = (char*)d_ws;
  size_t off = 0;
  auto alloc = [&](size_t bytes) -> void* {
    void* p = ws + off;
    off += (bytes + 255) & ~(size_t)255;
    return p;
  };
  // zero-region: m(3x65536) Wc(27x3072) Wo(27x1024) MUST be contiguous
  float* mz    = (float*)alloc((size_t)307200 * 4);          // 1.2MB
  float* mbuf  = mz;                                         // 3 x 8192 x 8
  float* Wc    = mz + 196608;                                // 27 x 3072
  float* Wo    = mz + 196608 + 82944;                        // 27 x 1024
  bf16* xb     = (bf16*)alloc((size_t)8192 * 1024 * 2);      // 16MB
  bf16* Wqkvt  = (bf16*)alloc((size_t)3072 * 1024 * 2);      // 6MB [3072][1024]
  bf16* Woutt  = (bf16*)alloc((size_t)1024 * 1024 * 2);      // 2MB
  bf16* G      = (bf16*)alloc((size_t)8192 * 3072 * 2);      // 48MB [8192][3072]
  bf16* Q      = (bf16*)alloc((size_t)8192 * 1024 * 2);      // 16MB [B,H,S,HD] flowed
  bf16* Kt     = (bf16*)alloc((size_t)8192 * 1024 * 2);      // 16MB [B,H,S,HD] flowed
  bf16* Vt     = (bf16*)alloc((size_t)8192 * 1024 * 2);      // 16MB [B,H,HD,S]
  (void)ws_size; (void)in_sizes; (void)n_in; (void)out_size;

  prep_kernel<<<8192, 256, 0, stream>>>(x, xb, mz);
  transpose_cast<<<dim3(96, 32), 256, 0, stream>>>(W_qkv, Wqkvt, 1024, 3072);
  transpose_cast<<<dim3(32, 32), 256, 0, stream>>>(W_out, Woutt, 1024, 1024);
  wcomb_kernel<<<dim3(12, 8), 256, 0, stream>>>(W_qkv, W_attn, b_attn, Wc, 3072);
  wcomb_kernel<<<dim3(4, 8), 256, 0, stream>>>(W_out, W_attn, b_attn, Wo, 1024);

  // G = x @ W_qkv + b_qkv  (the ONLY large qkv GEMM)
  gemm_bt<1><<<dim3(64, 24), 256, 0, stream>>>(xb, Wqkvt, b_qkv, G, nullptr,
                                               8192, 3072, 1024);
  // layer 0
  corr_kernel<0><<<dim3(24, 128), 256, 0, stream>>>(G, mbuf, b_pinv, Wc, Q, Kt, Vt);
  attn_kernel<<<dim3(64, 8), 256, 0, stream>>>(Q, Kt, Vt, W_pinv, mbuf);
  // layer 1
  corr_kernel<1><<<dim3(24, 128), 256, 0, stream>>>(G, mbuf, b_pinv, Wc, Q, Kt, Vt);
  attn_kernel<<<dim3(64, 8), 256, 0, stream>>>(Q, Kt, Vt, W_pinv, mbuf + 65536);
  // layer 2
  corr_kernel<2><<<dim3(24, 128), 256, 0, stream>>>(G, mbuf, b_pinv, Wc, Q, Kt, Vt);
  attn_kernel<<<dim3(64, 8), 256, 0, stream>>>(Q, Kt, Vt, W_pinv, mbuf + 131072);
  // out = x @ W_out + b_out  (plain GEMM), then rank-27 correction RMW
  gemm_bt<0><<<dim3(64, 8), 256, 0, stream>>>(xb, Woutt, b_out, nullptr,
                                              (float*)d_out, 8192, 1024, 1024);
  outcorr_kernel<<<8192, 256, 0, stream>>>((float*)d_out, mbuf, b_pinv, Wo);
}

// Round 7
// 565.099 us; speedup vs baseline: 2.3315x; 1.2512x over previous
//
#include <hip/hip_runtime.h>
#include <hip/hip_bf16.h>
#include <cstdint>

typedef __hip_bfloat16 bf16;
typedef __bf16 b8 __attribute__((ext_vector_type(8)));
typedef float f4v __attribute__((ext_vector_type(4)));
typedef short s8v __attribute__((ext_vector_type(8)));

#define DEVI static __device__ __forceinline__

// async global->LDS, 16B per lane. LDS dest is wave-uniform base + lane*16.
DEVI void gload16(const void* g, void* l) {
  __builtin_amdgcn_global_load_lds(
      (const __attribute__((address_space(1))) void*)(uintptr_t)g,
      (__attribute__((address_space(3))) void*)(uint32_t)(uintptr_t)l,
      16, 0, 0);
}

DEVI f4v mfma_bf16(b8 a, b8 b, f4v c) {
  return __builtin_amdgcn_mfma_f32_16x16x32_bf16(a, b, c, 0, 0, 0);
}

// ---------------------------------------------------------------------------
// prep: x -> xb (bf16); zero Wc (27x3072) + Wo (27x1024) region (110592 floats)
// ---------------------------------------------------------------------------
__global__ void prep_kernel(const float* __restrict__ x, bf16* __restrict__ xb,
                            float* __restrict__ zbase) {
  int gid = blockIdx.x * 256 + threadIdx.x;
  int i = gid * 4;
  float4 v = *(const float4*)(x + i);
  __hip_bfloat162 a, b;
  a.x = __float2bfloat16(v.x); a.y = __float2bfloat16(v.y);
  b.x = __float2bfloat16(v.z); b.y = __float2bfloat16(v.w);
  *(__hip_bfloat162*)(xb + i) = a;
  *(__hip_bfloat162*)(xb + i + 2) = b;
  if (gid < 110592) zbase[gid] = 0.f;  // 82944 Wc + 27648 Wo
}

// ---------------------------------------------------------------------------
// transpose + cast fp32 [R][C] -> bf16 [C][R]   (weights, tiny)
// ---------------------------------------------------------------------------
__global__ void transpose_cast(const float* __restrict__ in, bf16* __restrict__ out,
                               int R, int C) {
  __shared__ float tile[32][33];
  int c0 = blockIdx.x * 32, r0 = blockIdx.y * 32;
  int tx = threadIdx.x & 31, ty = threadIdx.x >> 5;  // 32 x 8
  for (int rr = ty; rr < 32; rr += 8)
    tile[rr][tx] = in[(size_t)(r0 + rr) * C + c0 + tx];
  __syncthreads();
  for (int cc = ty; cc < 32; cc += 8)
    out[(size_t)(c0 + cc) * R + r0 + tx] = __float2bfloat16(tile[tx][cc]);
}

// ---------------------------------------------------------------------------
// wcomb: out[i*9+j][n] = sum_k row(i,j)[k] * Wsrc[k][n]; row j<8 = W_attn[i][j],
// j=8 = b_attn[i]. k split into 8 chunks, atomicAdd (out pre-zeroed; tiny).
// ---------------------------------------------------------------------------
__global__ void wcomb_kernel(const float* __restrict__ Wsrc,
                             const float* __restrict__ W_attn,
                             const float* __restrict__ b_attn,
                             float* __restrict__ out, int nout) {
  int n = blockIdx.x * 256 + threadIdx.x;
  int k0 = blockIdx.y * 128;
  float a[27];
#pragma unroll
  for (int c = 0; c < 27; c++) a[c] = 0.f;
  for (int k = k0; k < k0 + 128; k++) {
    float wv = Wsrc[(size_t)k * nout + n];
#pragma unroll
    for (int i = 0; i < 3; i++) {
#pragma unroll
      for (int j = 0; j < 8; j++) a[i * 9 + j] += W_attn[(i * 8 + j) * 1024 + k] * wv;
      a[i * 9 + 8] += b_attn[i * 1024 + k] * wv;
    }
  }
#pragma unroll
  for (int c = 0; c < 27; c++) atomicAdd(&out[(size_t)c * nout + n], a[c]);
}

// ---------------------------------------------------------------------------
// GEMM: C[M,N] = A[M,K](bf16,rm) @ Bt[N,K](bf16,rm)^T + bias
// 128x128 tile, BK=64, 4 waves of 4x4 16x16x32 MFMA tiles. Register-light
// epilogues ONLY (acc stays in AGPRs -> no spill).
// MODE 0: write fp32 C row-major.  MODE 1: write bf16 C row-major (G).
// ---------------------------------------------------------------------------
template <int MODE>
__global__ __launch_bounds__(256, 3)
void gemm_bt(const bf16* __restrict__ A, const bf16* __restrict__ Bt,
             const float* __restrict__ bias, bf16* __restrict__ Gout,
             float* __restrict__ Cf, int M, int N, int K) {
  __shared__ bf16 As[128 * 64];
  __shared__ bf16 Bs[128 * 64];
  const int t = threadIdx.x;
  const int w = t >> 6, lane = t & 63;
  const int lm = lane & 15, qd = lane >> 4;
  const int m0 = blockIdx.x * 128, n0 = blockIdx.y * 128;
  const int wm = (w & 1) * 64, wn = (w >> 1) * 64;

  const bf16* Ag = A + (size_t)m0 * K;
  const bf16* Bg = Bt + (size_t)n0 * K;

  f4v acc[4][4];
  f4v zero = {0.f, 0.f, 0.f, 0.f};
#pragma unroll
  for (int i = 0; i < 4; i++)
#pragma unroll
    for (int j = 0; j < 4; j++) acc[i][j] = zero;

  for (int k0 = 0; k0 < K; k0 += 64) {
#pragma unroll
    for (int c = 0; c < 4; c++) {
      int s = c * 256 + t;
      int r = s >> 3;
      int kc = (s & 7) ^ (r & 7);  // xor-swizzle: same 128B row, permuted 16B chunks
      gload16(Ag + (size_t)r * K + k0 + kc * 8, &As[s * 8]);
      gload16(Bg + (size_t)r * K + k0 + kc * 8, &Bs[s * 8]);
    }
    __syncthreads();
#pragma unroll
    for (int ks = 0; ks < 2; ks++) {
      b8 af[4], bfr[4];
#pragma unroll
      for (int tm = 0; tm < 4; tm++) {
        int row = wm + tm * 16 + lm;
        int ch = (ks * 4 + qd) ^ (row & 7);
        af[tm] = *(const b8*)&As[row * 64 + ch * 8];
      }
#pragma unroll
      for (int tn = 0; tn < 4; tn++) {
        int row = wn + tn * 16 + lm;
        int ch = (ks * 4 + qd) ^ (row & 7);
        bfr[tn] = *(const b8*)&Bs[row * 64 + ch * 8];
      }
#pragma unroll
      for (int tm = 0; tm < 4; tm++)
#pragma unroll
        for (int tn = 0; tn < 4; tn++)
          acc[tm][tn] = mfma_bf16(af[tm], bfr[tn], acc[tm][tn]);
    }
    __syncthreads();
  }

#pragma unroll
  for (int tn = 0; tn < 4; tn++) {
    int col = n0 + wn + tn * 16 + lm;
    float bv = bias[col];
#pragma unroll
    for (int tm = 0; tm < 4; tm++)
#pragma unroll
      for (int r = 0; r < 4; r++) {
        int row = m0 + wm + tm * 16 + qd * 4 + r;  // C layout: row=(lane>>4)*4+reg
        if (MODE == 1)
          Gout[(size_t)row * N + col] = __float2bfloat16(acc[tm][tn][r] + bv);
        else
          Cf[(size_t)row * N + col] = acc[tm][tn][r] + bv;
      }
  }
}

// ---------------------------------------------------------------------------
// outcorr: out[row][col] += sum_i ((m_i[row]+bpinv) @ Wo_i[:,col] + Wo_i[8][col])
// m_i[row][j] reduced in-kernel from mpart (8 heads). Memory-bound RMW.
// ---------------------------------------------------------------------------
__global__ __launch_bounds__(256)
void outcorr_kernel(float* __restrict__ out, const float* __restrict__ mpart,
                    const float* __restrict__ bpinv, const float* __restrict__ Wo) {
  const int row = blockIdx.x;
  const int b = row >> 10, sl = row & 1023;
  const int h0 = threadIdx.x * 4;
  __shared__ float sm[24];
  if (threadIdx.x < 24) {
    int i = threadIdx.x >> 3, j = threadIdx.x & 7;
    float a = 0.f;
#pragma unroll
    for (int h2 = 0; h2 < 8; h2++)
      a += mpart[(size_t)i * 524288 + (((size_t)(b * 8 + h2) * 1024 + sl) * 8 + j)];
    sm[threadIdx.x] = a + bpinv[j];
  }
  __syncthreads();
  float u[4] = {0.f, 0.f, 0.f, 0.f};
#pragma unroll
  for (int i = 0; i < 3; i++)
#pragma unroll
    for (int j = 0; j < 9; j++) {
      float4 wv = *(const float4*)(Wo + (size_t)(i * 9 + j) * 1024 + h0);
      float mj = (j < 8) ? sm[i * 8 + j] : 1.0f;
      u[0] += mj * wv.x; u[1] += mj * wv.y; u[2] += mj * wv.z; u[3] += mj * wv.w;
    }
  float4 c4 = *(float4*)(out + (size_t)row * 1024 + h0);
  c4.x += u[0]; c4.y += u[1]; c4.z += u[2]; c4.w += u[3];
  *(float4*)(out + (size_t)row * 1024 + h0) = c4;
}

// ---------------------------------------------------------------------------
// corr<NL>: qkv_l = G + sum_{i<NL} (m_i+bpinv)@Wc_i + Wc_i[8]; m_i reduced from
// mpart (8 heads) into LDS at block start (coalesced, L2-resident).
// part 0/1 (Q/K): fused expmap0 (+1/sqrt(128) for Q) — 8-row-batched shfl
// butterflies (independent chains, latency-pipelined). part 2 (V):
// LDS-transpose (stride 66), coalesced uint4 stores to Vt[bh][d][s].
// Block: 64 s-rows x 128 d-cols of one (part,head). Lane owns d=lane, lane+64.
// ---------------------------------------------------------------------------
template <int NL>
__global__ __launch_bounds__(256, 4)
void corr_kernel(const bf16* __restrict__ G, const float* __restrict__ mpart,
                 const float* __restrict__ bpinv, const float* __restrict__ Wc,
                 bf16* __restrict__ Qo, bf16* __restrict__ Ko,
                 bf16* __restrict__ Vto) {
  __shared__ bf16 Gs[64 * 128];
  __shared__ bf16 VtT[128 * 66];
  __shared__ float mvs[NL > 0 ? NL : 1][64][8];
  const int t = threadIdx.x, w = t >> 6, lane = t & 63;
  const int ph = blockIdx.x;  // 0..23
  const int part = ph >> 3, h = ph & 7;
  const int sy = blockIdx.y;  // 0..127
  const int n0 = part * 1024 + h * 128;

#pragma unroll
  for (int c = 0; c < 4; c++) {
    int slot = c * 256 + t;
    int row = slot >> 4, ch = slot & 15;
    gload16(G + (size_t)(sy * 64 + row) * 3072 + n0 + ch * 8, &Gs[slot * 8]);
  }
  // while the DMA is in flight: reduce mpart (8 heads) for this block's 64 rows
#pragma unroll
  for (int i = 0; i < NL; i++)
    for (int v = t; v < 512; v += 256) {
      int row = v >> 3, j = v & 7;
      int s = sy * 64 + row;
      int b = s >> 10, sl = s & 1023;
      float a = 0.f;
#pragma unroll
      for (int h2 = 0; h2 < 8; h2++)
        a += mpart[(size_t)i * 524288 +
                   (((size_t)(b * 8 + h2) * 1024 + sl) * 8 + j)];
      mvs[i][row][j] = a + bpinv[j];
    }
  __syncthreads();

  float wca[NL > 0 ? NL : 1][9], wcb[NL > 0 ? NL : 1][9];
#pragma unroll
  for (int i = 0; i < NL; i++)
#pragma unroll
    for (int j = 0; j < 9; j++) {
      wca[i][j] = Wc[(size_t)(i * 9 + j) * 3072 + n0 + lane];
      wcb[i][j] = Wc[(size_t)(i * 9 + j) * 3072 + n0 + lane + 64];
    }

  if (part < 2) {
    const float qsc = (part == 0) ? 0.08838834764831845f : 1.0f;  // 1/sqrt(128)
    bf16* dst = (part == 0) ? Qo : Ko;
#pragma unroll
    for (int half = 0; half < 2; half++) {
      float g0a[8], g1a[8], ssv[8];
#pragma unroll
      for (int rr = 0; rr < 8; rr++) {
        int row = w * 16 + half * 8 + rr;
        float g0 = __bfloat162float(Gs[row * 128 + lane]);
        float g1 = __bfloat162float(Gs[row * 128 + lane + 64]);
#pragma unroll
        for (int i = 0; i < NL; i++) {
          g0 += wca[i][8];
          g1 += wcb[i][8];
#pragma unroll
          for (int j = 0; j < 8; j++) {
            float mj = mvs[i][row][j];
            g0 += mj * wca[i][j];
            g1 += mj * wcb[i][j];
          }
        }
        g0a[rr] = g0; g1a[rr] = g1;
        ssv[rr] = g0 * g0 + g1 * g1;
      }
      // 8 independent butterflies — latency pipelined
#pragma unroll
      for (int off = 32; off; off >>= 1)
#pragma unroll
        for (int rr = 0; rr < 8; rr++) ssv[rr] += __shfl_xor(ssv[rr], off, 64);
#pragma unroll
      for (int rr = 0; rr < 8; rr++) {
        int row = w * 16 + half * 8 + rr;
        int s = sy * 64 + row;
        float n = fmaxf(sqrtf(ssv[rr]), 1e-7f);
        float sc = tanhf(n) / n * qsc;
        int b = s >> 10, sIdx = s & 1023;
        bf16* drow = dst + (((size_t)(b * 8 + h)) * 1024 + sIdx) * 128;
        drow[lane] = __float2bfloat16(g0a[rr] * sc);
        drow[lane + 64] = __float2bfloat16(g1a[rr] * sc);
      }
    }
  } else {
    for (int rr = 0; rr < 16; rr++) {
      int row = w * 16 + rr;
      float g0 = __bfloat162float(Gs[row * 128 + lane]);
      float g1 = __bfloat162float(Gs[row * 128 + lane + 64]);
#pragma unroll
      for (int i = 0; i < NL; i++) {
        g0 += wca[i][8];
        g1 += wcb[i][8];
#pragma unroll
        for (int j = 0; j < 8; j++) {
          float mj = mvs[i][row][j];
          g0 += mj * wca[i][j];
          g1 += mj * wcb[i][j];
        }
      }
      VtT[lane * 66 + row] = __float2bfloat16(g0);
      VtT[(lane + 64) * 66 + row] = __float2bfloat16(g1);
    }
    __syncthreads();
    int d = t >> 1, half = t & 1;
    int s0g = sy * 64;
    int b = s0g >> 10, sIdx0 = s0g & 1023;
    bf16* orow = Vto + ((size_t)(b * 8 + h)) * 131072 + (size_t)d * 1024 + sIdx0 +
                 half * 32;
#pragma unroll
    for (int i = 0; i < 4; i++) {
      uint32_t u[4];
#pragma unroll
      for (int c = 0; c < 4; c++)
        u[c] = *(const uint32_t*)&VtT[d * 66 + half * 32 + i * 8 + c * 2];
      uint4 pk = make_uint4(u[0], u[1], u[2], u[3]);
      *(uint4*)&orow[i * 8] = pk;
    }
  }
}

// ---------------------------------------------------------------------------
// Flash attention, no-max softmax (|score| <= 1/sqrt(128); exp in [0.915,1.092]).
// l via MFMA against all-ones B. grid (64 bh, 8 qt) => same-bh same-XCD.
// 4 waves x 32 q-rows; K-fragments shared across both m-tiles.
// Epilogue: m-partials per (b,h) -> PLAIN float4 stores to mpart (no atomics;
// consumers reduce the 8 heads). R6 lesson: 524k far-atomics => 16 MB of
// line-granular HBM RMW + ~35us drain tail.
// ---------------------------------------------------------------------------
__global__ __launch_bounds__(256, 2)
void attn_kernel(const bf16* __restrict__ Qf, const bf16* __restrict__ Kf,
                 const bf16* __restrict__ Vt, const float* __restrict__ Wpinv,
                 float* __restrict__ mpart) {
  __shared__ bf16 smem[24576];            // 49152 B
  bf16* Ks = smem;                        // [64 s'][128 d] chunk-swizzled
  bf16* Vs = smem + 8192;                 // [128 d][64 s'] chunk-swizzled
  bf16* Ps = smem + 16384;                // [4 waves][32 q][64 s'] perm-swizzled
  const int t = threadIdx.x, w = t >> 6, lane = t & 63;
  const int lm = lane & 15, qd = lane >> 4;
  const int bh = blockIdx.x, qt = blockIdx.y;
  const bf16* Qg = Qf + ((size_t)bh * 1024 + qt * 128) * 128;
  const bf16* Kg = Kf + (size_t)bh * 131072;
  const bf16* Vg = Vt + (size_t)bh * 131072;
  bf16* Pw = Ps + w * 2048;

  b8 qfr[2][4];
#pragma unroll
  for (int mt = 0; mt < 2; mt++)
#pragma unroll
    for (int ks = 0; ks < 4; ks++)
      qfr[mt][ks] =
          *(const b8*)(Qg + (size_t)(w * 32 + mt * 16 + lm) * 128 + ks * 32 + qd * 8);

  f4v o[2][8];
  f4v lacc[2];
  f4v zero = {0.f, 0.f, 0.f, 0.f};
#pragma unroll
  for (int mt = 0; mt < 2; mt++) {
    lacc[mt] = zero;
#pragma unroll
    for (int i = 0; i < 8; i++) o[mt][i] = zero;
  }
  union { s8v s; b8 b; } uo;
#pragma unroll
  for (int i = 0; i < 8; i++) uo.s[i] = 0x3F80;  // bf16 1.0
  const b8 ones = uo.b;

  for (int kt = 0; kt < 16; kt++) {
    __syncthreads();
#pragma unroll
    for (int c = 0; c < 4; c++) {
      int s = c * 256 + t;
      int r = s >> 4;
      int kc = (s & 15) ^ (r & 7);
      gload16(Kg + (size_t)(kt * 64 + r) * 128 + kc * 8, &Ks[s * 8]);
      int rv = s >> 3;
      int kv = (s & 7) ^ (rv & 7);
      gload16(Vg + (size_t)rv * 1024 + kt * 64 + kv * 8, &Vs[s * 8]);
    }
    __syncthreads();

    f4v sc[2][4];
#pragma unroll
    for (int mt = 0; mt < 2; mt++)
#pragma unroll
      for (int tn = 0; tn < 4; tn++) sc[mt][tn] = zero;
#pragma unroll
    for (int tn = 0; tn < 4; tn++) {
      int krow = tn * 16 + lm;
#pragma unroll
      for (int ks = 0; ks < 4; ks++) {
        int ch = (ks * 4 + qd) ^ (krow & 7);
        b8 kfr = *(const b8*)&Ks[krow * 128 + ch * 8];
        sc[0][tn] = mfma_bf16(qfr[0][ks], kfr, sc[0][tn]);
        sc[1][tn] = mfma_bf16(qfr[1][ks], kfr, sc[1][tn]);
      }
    }
#pragma unroll
    for (int mt = 0; mt < 2; mt++)
#pragma unroll
      for (int tn = 0; tn < 4; tn++)
#pragma unroll
        for (int r = 0; r < 4; r++) {
          int qi = mt * 16 + qd * 4 + r;
          int ch = (tn * 2 + (lm >> 3)) ^ ((qi >> 1) & 7);
          Pw[qi * 64 + ch * 8 + (lm & 7)] = __float2bfloat16(__expf(sc[mt][tn][r]));
        }

    b8 pa[2][2];
#pragma unroll
    for (int mt = 0; mt < 2; mt++)
#pragma unroll
      for (int kv2 = 0; kv2 < 2; kv2++) {
        int qi = mt * 16 + lm;
        int ch = (kv2 * 4 + qd) ^ ((lm >> 1) & 7);
        pa[mt][kv2] = *(const b8*)&Pw[qi * 64 + ch * 8];
      }
#pragma unroll
    for (int mt = 0; mt < 2; mt++)
#pragma unroll
      for (int kv2 = 0; kv2 < 2; kv2++)
        lacc[mt] = mfma_bf16(pa[mt][kv2], ones, lacc[mt]);
#pragma unroll
    for (int tnd = 0; tnd < 8; tnd++) {
      int drow = tnd * 16 + lm;
#pragma unroll
      for (int kv2 = 0; kv2 < 2; kv2++) {
        int ch = (kv2 * 4 + qd) ^ (drow & 7);
        b8 vfr = *(const b8*)&Vs[drow * 64 + ch * 8];
#pragma unroll
        for (int mt = 0; mt < 2; mt++)
          o[mt][tnd] = mfma_bf16(pa[mt][kv2], vfr, o[mt][tnd]);
      }
    }
  }

  // epilogue: project o (normalized) onto W_pinv -> per-(b,h) m partials
#pragma unroll
  for (int mt = 0; mt < 2; mt++) {
    float rinv[4];
#pragma unroll
    for (int r = 0; r < 4; r++) rinv[r] = 1.0f / lacc[mt][r];
    float msum[4][8];
#pragma unroll
    for (int r = 0; r < 4; r++)
#pragma unroll
      for (int j = 0; j < 8; j++) msum[r][j] = 0.f;
#pragma unroll
    for (int tnd = 0; tnd < 8; tnd++) {
      int d = tnd * 16 + lm;
      const int h = bh & 7;
      const float* wp = Wpinv + (size_t)(h * 128 + d) * 8;
      float4 wa = *(const float4*)wp;
      float4 wb = *(const float4*)(wp + 4);
#pragma unroll
      for (int r = 0; r < 4; r++) {
        float on = o[mt][tnd][r] * rinv[r];
        msum[r][0] += on * wa.x; msum[r][1] += on * wa.y;
        msum[r][2] += on * wa.z; msum[r][3] += on * wa.w;
        msum[r][4] += on * wb.x; msum[r][5] += on * wb.y;
        msum[r][6] += on * wb.z; msum[r][7] += on * wb.w;
      }
    }
#pragma unroll
    for (int r = 0; r < 4; r++)
#pragma unroll
      for (int j = 0; j < 8; j++)
#pragma unroll
        for (int off = 1; off < 16; off <<= 1)
          msum[r][j] += __shfl_xor(msum[r][j], off, 64);
    if (lm == 0) {
#pragma unroll
      for (int r = 0; r < 4; r++) {
        int sIdx = qt * 128 + w * 32 + mt * 16 + qd * 4 + r;
        float* md = mpart + ((size_t)bh * 1024 + sIdx) * 8;
        float4 lo = make_float4(msum[r][0], msum[r][1], msum[r][2], msum[r][3]);
        float4 hi = make_float4(msum[r][4], msum[r][5], msum[r][6], msum[r][7]);
        *(float4*)md = lo;
        *(float4*)(md + 4) = hi;
      }
    }
  }
}

// ---------------------------------------------------------------------------
extern "C" void kernel_launch(void* const* d_in, const int* in_sizes, int n_in,
                              void* d_out, int out_size, void* d_ws, size_t ws_size,
                              hipStream_t stream) {
  const float* x      = (const float*)d_in[0];
  const float* W_qkv  = (const float*)d_in[1];
  const float* b_qkv  = (const float*)d_in[2];
  const float* W_pinv = (const float*)d_in[3];
  const float* b_pinv = (const float*)d_in[4];
  const float* W_attn = (const float*)d_in[5];
  const float* b_attn = (const float*)d_in[6];
  const float* W_out  = (const float*)d_in[7];
  const float* b_out  = (const float*)d_in[8];

  char* ws = (char*)d_ws;
  size_t off = 0;
  auto alloc = [&](size_t bytes) -> void* {
    void* p = ws + off;
    off += (bytes + 255) & ~(size_t)255;
    return p;
  };
  // zero-region: Wc(27x3072) Wo(27x1024) contiguous (110592 floats)
  float* Wc    = (float*)alloc((size_t)110592 * 4);
  float* Wo    = Wc + 82944;
  float* mpart = (float*)alloc((size_t)3 * 524288 * 4);      // 6MB [l][bh][s][8]
  bf16* xb     = (bf16*)alloc((size_t)8192 * 1024 * 2);      // 16MB
  bf16* Wqkvt  = (bf16*)alloc((size_t)3072 * 1024 * 2);      // 6MB [3072][1024]
  bf16* Woutt  = (bf16*)alloc((size_t)1024 * 1024 * 2);      // 2MB
  bf16* G      = (bf16*)alloc((size_t)8192 * 3072 * 2);      // 48MB [8192][3072]
  bf16* Q      = (bf16*)alloc((size_t)8192 * 1024 * 2);      // 16MB [B,H,S,HD] flowed
  bf16* Kt     = (bf16*)alloc((size_t)8192 * 1024 * 2);      // 16MB [B,H,S,HD] flowed
  bf16* Vt     = (bf16*)alloc((size_t)8192 * 1024 * 2);      // 16MB [B,H,HD,S]
  (void)ws_size; (void)in_sizes; (void)n_in; (void)out_size;

  prep_kernel<<<8192, 256, 0, stream>>>(x, xb, Wc);
  transpose_cast<<<dim3(96, 32), 256, 0, stream>>>(W_qkv, Wqkvt, 1024, 3072);
  transpose_cast<<<dim3(32, 32), 256, 0, stream>>>(W_out, Woutt, 1024, 1024);
  wcomb_kernel<<<dim3(12, 8), 256, 0, stream>>>(W_qkv, W_attn, b_attn, Wc, 3072);
  wcomb_kernel<<<dim3(4, 8), 256, 0, stream>>>(W_out, W_attn, b_attn, Wo, 1024);

  // G = x @ W_qkv + b_qkv  (the ONLY large qkv GEMM)
  gemm_bt<1><<<dim3(64, 24), 256, 0, stream>>>(xb, Wqkvt, b_qkv, G, nullptr,
                                               8192, 3072, 1024);
  // layer 0
  corr_kernel<0><<<dim3(24, 128), 256, 0, stream>>>(G, mpart, b_pinv, Wc, Q, Kt, Vt);
  attn_kernel<<<dim3(64, 8), 256, 0, stream>>>(Q, Kt, Vt, W_pinv, mpart);
  // layer 1
  corr_kernel<1><<<dim3(24, 128), 256, 0, stream>>>(G, mpart, b_pinv, Wc, Q, Kt, Vt);
  attn_kernel<<<dim3(64, 8), 256, 0, stream>>>(Q, Kt, Vt, W_pinv, mpart + 524288);
  // layer 2
  corr_kernel<2><<<dim3(24, 128), 256, 0, stream>>>(G, mpart, b_pinv, Wc, Q, Kt, Vt);
  attn_kernel<<<dim3(64, 8), 256, 0, stream>>>(Q, Kt, Vt, W_pinv, mpart + 1048576);
  // out = x @ W_out + b_out  (plain GEMM), then rank-27 correction RMW
  gemm_bt<0><<<dim3(64, 8), 256, 0, stream>>>(xb, Woutt, b_out, nullptr,
                                              (float*)d_out, 8192, 1024, 1024);
  outcorr_kernel<<<8192, 256, 0, stream>>>((float*)d_out, mpart, b_pinv, Wo);
}